// Round 1
// baseline (412.462 us; speedup 1.0000x reference)
//
#include <hip/hip_runtime.h>
#include <math.h>

#define BS   16
#define CH   256
#define NPIX 16384   // 128*128
#define TOPK 12

// ---------------------------------------------------------------------------
// Kernel A: compute softmax over the 2 logit channels, pack fg/bg mask bits
// into one byte per pixel, and accumulate per-batch mask counts.
// Grid: BS * (NPIX/256) = 1024 blocks of 256 threads.
// ---------------------------------------------------------------------------
__global__ __launch_bounds__(256) void mask_kernel(
    const float* __restrict__ outp,   // (BS, 2, NPIX)
    const float* __restrict__ tau,    // scalar
    unsigned char* __restrict__ masks, // (BS, NPIX) bytes: bit0=fg, bit1=bg
    int* __restrict__ cnts)            // [0..BS) fg counts, [BS..2BS) bg counts
{
    int b = blockIdx.x >> 6;                       // 64 blocks per batch
    int n = ((blockIdx.x & 63) << 8) + threadIdx.x;

    float t = tau[0];
    float fthres = 1.0f / (1.0f + expf(-t));
    float bthres = 1.0f - fthres;

    float o0 = outp[((size_t)b * 2    ) * NPIX + n];
    float o1 = outp[((size_t)b * 2 + 1) * NPIX + n];
    // mirror jax.nn.softmax: exp(x - max) / sum
    float m  = fmaxf(o0, o1);
    float e0 = expf(o0 - m);
    float e1 = expf(o1 - m);
    float inv = 1.0f / (e0 + e1);
    float pf = e1 * inv;   // pred_fg
    float pb = e0 * inv;   // pred_bg

    int fg = pf > fthres ? 1 : 0;
    int bg = pb > bthres ? 1 : 0;
    masks[((size_t)b << 14) + n] = (unsigned char)(fg | (bg << 1));

    unsigned long long balf = __ballot(fg);
    unsigned long long balb = __ballot(bg);
    if ((threadIdx.x & 63) == 0) {
        atomicAdd(&cnts[b],      (int)__popcll(balf));
        atomicAdd(&cnts[BS + b], (int)__popcll(balb));
    }
}

// ---------------------------------------------------------------------------
// Kernel B (the HBM-bound one): per (b,c), masked sums over NPIX for both
// fg and bg in one pass over feature_q. Writes RAW SUMS into d_out:
//   d_out[0      .. BS*CH)  = fg sums
//   d_out[BS*CH .. 2*BS*CH) = bg sums
// Grid: BS*CH = 4096 blocks of 256 threads; each block streams 64 KB.
// ---------------------------------------------------------------------------
__global__ __launch_bounds__(256) void sum_kernel(
    const float* __restrict__ feat,           // (BS, CH, NPIX)
    const unsigned char* __restrict__ masks,  // (BS, NPIX)
    float* __restrict__ dout)
{
    int b = blockIdx.x >> 8;
    int c = blockIdx.x & (CH - 1);

    const float4* fp = (const float4*)(feat + (((size_t)b * CH + c) << 14));
    const uchar4* mp = (const uchar4*)(masks + ((size_t)b << 14));

    float sfg = 0.0f, sbg = 0.0f;
    #pragma unroll
    for (int i = 0; i < 16; ++i) {
        int idx = i * 256 + threadIdx.x;
        float4 f = fp[idx];
        uchar4 mm = mp[idx];
        if (mm.x & 1) sfg += f.x;
        if (mm.y & 1) sfg += f.y;
        if (mm.z & 1) sfg += f.z;
        if (mm.w & 1) sfg += f.w;
        if (mm.x & 2) sbg += f.x;
        if (mm.y & 2) sbg += f.y;
        if (mm.z & 2) sbg += f.z;
        if (mm.w & 2) sbg += f.w;
    }

    // wave (64-lane) reduction, then cross-wave via LDS
    #pragma unroll
    for (int off = 32; off > 0; off >>= 1) {
        sfg += __shfl_down(sfg, off);
        sbg += __shfl_down(sbg, off);
    }
    __shared__ float shf[4], shb[4];
    int lane = threadIdx.x & 63, wid = threadIdx.x >> 6;
    if (lane == 0) { shf[wid] = sfg; shb[wid] = sbg; }
    __syncthreads();
    if (threadIdx.x == 0) {
        float tf = shf[0] + shf[1] + shf[2] + shf[3];
        float tb = shb[0] + shb[1] + shb[2] + shb[3];
        dout[b * CH + c]           = tf;
        dout[BS * CH + b * CH + c] = tb;
    }
}

// ---------------------------------------------------------------------------
// Kernel C: finalize. One block per (b, which): 2*BS = 32 blocks, 256 thr.
// cnt>0 (common): divide sums in place. cnt==0 (rare): exact top-12 of the
// softmax prob (desc value, asc index ties — matches jax.lax.top_k), then
// per-channel gather-mean.
// ---------------------------------------------------------------------------
__global__ __launch_bounds__(256) void finalize_kernel(
    const float* __restrict__ feat,
    const float* __restrict__ outp,
    const float* __restrict__ tau,
    const int* __restrict__ cnts,
    float* __restrict__ dout)
{
    int b     = blockIdx.x >> 1;
    int which = blockIdx.x & 1;   // 0 = fg, 1 = bg
    int cnt   = cnts[which * BS + b];
    float* o  = dout + (size_t)which * BS * CH + (size_t)b * CH;

    if (cnt > 0) {
        o[threadIdx.x] = o[threadIdx.x] / (float)cnt;
        return;
    }

    // ---- top-k fallback (block-uniform branch) ----
    __shared__ int   sel[TOPK];
    __shared__ float shv[256];
    __shared__ int   shi[256];

    const float* o0p = outp + ((size_t)b * 2) * NPIX;
    const float* o1p = o0p + NPIX;

    for (int k = 0; k < TOPK; ++k) {
        float bestv = -INFINITY;
        int   besti = 0x7fffffff;
        for (int n = threadIdx.x; n < NPIX; n += 256) {
            bool skip = false;
            for (int j = 0; j < k; ++j) if (sel[j] == n) { skip = true; break; }
            if (skip) continue;
            float a0 = o0p[n], a1 = o1p[n];
            float m  = fmaxf(a0, a1);
            float e0 = expf(a0 - m);
            float e1 = expf(a1 - m);
            float p  = (which == 0 ? e1 : e0) / (e0 + e1);
            if (p > bestv || (p == bestv && n < besti)) { bestv = p; besti = n; }
        }
        shv[threadIdx.x] = bestv;
        shi[threadIdx.x] = besti;
        __syncthreads();
        for (int off = 128; off > 0; off >>= 1) {
            if (threadIdx.x < off) {
                float v2 = shv[threadIdx.x + off];
                int   i2 = shi[threadIdx.x + off];
                if (v2 > shv[threadIdx.x] ||
                    (v2 == shv[threadIdx.x] && i2 < shi[threadIdx.x])) {
                    shv[threadIdx.x] = v2;
                    shi[threadIdx.x] = i2;
                }
            }
            __syncthreads();
        }
        if (threadIdx.x == 0) sel[k] = shi[0];
        __syncthreads();
    }

    // per-channel mean over the 12 selected pixels; c = threadIdx.x
    const float* fb = feat + ((size_t)b * CH + threadIdx.x) * (size_t)NPIX;
    float s = 0.0f;
    for (int j = 0; j < TOPK; ++j) s += fb[sel[j]];
    o[threadIdx.x] = s / (float)TOPK;
}

extern "C" void kernel_launch(void* const* d_in, const int* in_sizes, int n_in,
                              void* d_out, int out_size, void* d_ws, size_t ws_size,
                              hipStream_t stream) {
    const float* feat = (const float*)d_in[0];  // (16,256,128,128) fp32
    const float* outp = (const float*)d_in[1];  // (16,2,128,128)  fp32
    const float* tau  = (const float*)d_in[2];  // scalar fp32
    float* dout = (float*)d_out;                // 2 * 16*256 fp32

    unsigned char* masks = (unsigned char*)d_ws;             // BS*NPIX bytes = 256 KB
    int* cnts = (int*)((char*)d_ws + (size_t)BS * NPIX);     // 2*BS ints

    // counters must start at 0 (ws is poisoned 0xAA before every launch)
    hipMemsetAsync(cnts, 0, 2 * BS * sizeof(int), stream);

    mask_kernel<<<BS * (NPIX / 256), 256, 0, stream>>>(outp, tau, masks, cnts);
    sum_kernel<<<BS * CH, 256, 0, stream>>>(feat, masks, dout);
    finalize_kernel<<<2 * BS, 256, 0, stream>>>(feat, outp, tau, cnts, dout);
}

// Round 3
// 336.668 us; speedup vs baseline: 1.2251x; 1.2251x over previous
//
#include <hip/hip_runtime.h>
#include <math.h>
#include <stdint.h>

#define BS   16
#define CH   256
#define NPIX 16384        // 128*128
#define TOPK 12
#define WPB  (NPIX / 64)  // 256 uint64 mask words per batch

// clang-native float4 so __builtin_nontemporal_load accepts it
typedef float nfloat4 __attribute__((ext_vector_type(4)));

// ---------------------------------------------------------------------------
// Kernel A: softmax over the 2 logit channels -> fg/bg threshold bits, packed
// via __ballot into one uint64 per 64 pixels. No atomics, no zero-init needed
// (every word is written). Grid: BS * (NPIX/256) = 1024 blocks of 256.
// ---------------------------------------------------------------------------
__global__ __launch_bounds__(256) void mask_kernel(
    const float* __restrict__ outp,   // (BS, 2, NPIX)
    const float* __restrict__ tau,    // scalar
    uint64_t* __restrict__ mfg,       // (BS, WPB) fg bits
    uint64_t* __restrict__ mbg)       // (BS, WPB) bg bits
{
    int b = blockIdx.x >> 6;                       // 64 blocks per batch
    int n = ((blockIdx.x & 63) << 8) + threadIdx.x;

    float t = tau[0];
    float fthres = 1.0f / (1.0f + expf(-t));       // sigmoid(tau)
    float bthres = 1.0f - fthres;

    float o0 = outp[((size_t)b * 2    ) * NPIX + n];
    float o1 = outp[((size_t)b * 2 + 1) * NPIX + n];
    // mirror jax.nn.softmax: exp(x - max) / sum
    float m  = fmaxf(o0, o1);
    float e0 = expf(o0 - m);
    float e1 = expf(o1 - m);
    float inv = 1.0f / (e0 + e1);

    int fg = (e1 * inv) > fthres;   // pred_fg > fg_thres
    int bg = (e0 * inv) > bthres;   // pred_bg > bg_thres

    uint64_t bf = __ballot(fg);
    uint64_t bb = __ballot(bg);
    if ((threadIdx.x & 63) == 0) {
        int w = n >> 6;
        mfg[b * WPB + w] = bf;
        mbg[b * WPB + w] = bb;
    }
}

// ---------------------------------------------------------------------------
// Kernel B (HBM-bound): per (b,c) masked fg/bg sums over NPIX in one pass.
// Mask bits preloaded to LDS (4 KB) -> hot loop is pure feat streaming.
// Writes RAW SUMS: d_out[0..BS*CH) = fg, d_out[BS*CH..2*BS*CH) = bg.
// Grid: BS*CH = 4096 blocks of 256; each block streams 64 KB of feat.
// ---------------------------------------------------------------------------
__global__ __launch_bounds__(256) void sum_kernel(
    const float* __restrict__ feat,           // (BS, CH, NPIX)
    const uint64_t* __restrict__ mfg,
    const uint64_t* __restrict__ mbg,
    float* __restrict__ dout)
{
    int b = blockIdx.x >> 8;
    int c = blockIdx.x & (CH - 1);

    __shared__ uint64_t lf[WPB], lb[WPB];
    lf[threadIdx.x] = mfg[b * WPB + threadIdx.x];
    lb[threadIdx.x] = mbg[b * WPB + threadIdx.x];
    __syncthreads();

    const nfloat4* fp = (const nfloat4*)(feat + (((size_t)b * CH + c) << 14));

    float sfg = 0.0f, sbg = 0.0f;
    #pragma unroll
    for (int i = 0; i < 16; ++i) {
        int idx = i * 256 + threadIdx.x;
        nfloat4 f = __builtin_nontemporal_load(&fp[idx]);   // single-use stream
        int p = idx << 2;                                   // first pixel of the 4
        unsigned fb = (unsigned)(lf[p >> 6] >> (p & 63)) & 0xF;
        unsigned bb = (unsigned)(lb[p >> 6] >> (p & 63)) & 0xF;
        if (fb & 1) sfg += f.x;
        if (fb & 2) sfg += f.y;
        if (fb & 4) sfg += f.z;
        if (fb & 8) sfg += f.w;
        if (bb & 1) sbg += f.x;
        if (bb & 2) sbg += f.y;
        if (bb & 4) sbg += f.z;
        if (bb & 8) sbg += f.w;
    }

    // 64-lane wave reduction, then cross-wave via LDS
    #pragma unroll
    for (int off = 32; off > 0; off >>= 1) {
        sfg += __shfl_down(sfg, off);
        sbg += __shfl_down(sbg, off);
    }
    __shared__ float shf[4], shb[4];
    int lane = threadIdx.x & 63, wid = threadIdx.x >> 6;
    if (lane == 0) { shf[wid] = sfg; shb[wid] = sbg; }
    __syncthreads();
    if (threadIdx.x == 0) {
        dout[b * CH + c]           = shf[0] + shf[1] + shf[2] + shf[3];
        dout[BS * CH + b * CH + c] = shb[0] + shb[1] + shb[2] + shb[3];
    }
}

// ---------------------------------------------------------------------------
// Kernel C: finalize. One block per (b, which): 2*BS = 32 blocks, 256 thr.
// cnt from popcount of the packed mask (no atomics). cnt>0: divide in place.
// cnt==0 (rare, block-uniform): exact top-12 (desc value, asc index — matches
// jax.lax.top_k) of the softmax prob, then per-channel gather-mean.
// ---------------------------------------------------------------------------
__global__ __launch_bounds__(256) void finalize_kernel(
    const float* __restrict__ feat,
    const float* __restrict__ outp,
    const uint64_t* __restrict__ mfg,
    const uint64_t* __restrict__ mbg,
    float* __restrict__ dout)
{
    int b     = blockIdx.x >> 1;
    int which = blockIdx.x & 1;   // 0 = fg, 1 = bg
    const uint64_t* mw = which ? mbg : mfg;
    float* o = dout + (size_t)which * BS * CH + (size_t)b * CH;

    // popcount-reduce the batch's 256 mask words
    int pc = (int)__popcll(mw[b * WPB + threadIdx.x]);
    #pragma unroll
    for (int off = 32; off > 0; off >>= 1) pc += __shfl_down(pc, off);
    __shared__ int sw[4];
    if ((threadIdx.x & 63) == 0) sw[threadIdx.x >> 6] = pc;
    __syncthreads();
    int cnt = sw[0] + sw[1] + sw[2] + sw[3];

    if (cnt > 0) {
        o[threadIdx.x] = o[threadIdx.x] / (float)cnt;
        return;
    }

    // ---- top-k fallback (block-uniform branch) ----
    __shared__ int   sel[TOPK];
    __shared__ float shv[256];
    __shared__ int   shi[256];

    const float* o0p = outp + ((size_t)b * 2) * NPIX;
    const float* o1p = o0p + NPIX;

    for (int k = 0; k < TOPK; ++k) {
        float bestv = -INFINITY;
        int   besti = 0x7fffffff;
        for (int n = threadIdx.x; n < NPIX; n += 256) {
            bool skip = false;
            for (int j = 0; j < k; ++j) if (sel[j] == n) { skip = true; break; }
            if (skip) continue;
            float a0 = o0p[n], a1 = o1p[n];
            float m  = fmaxf(a0, a1);
            float e0 = expf(a0 - m);
            float e1 = expf(a1 - m);
            float p  = (which == 0 ? e1 : e0) / (e0 + e1);
            if (p > bestv || (p == bestv && n < besti)) { bestv = p; besti = n; }
        }
        shv[threadIdx.x] = bestv;
        shi[threadIdx.x] = besti;
        __syncthreads();
        for (int off = 128; off > 0; off >>= 1) {
            if (threadIdx.x < off) {
                float v2 = shv[threadIdx.x + off];
                int   i2 = shi[threadIdx.x + off];
                if (v2 > shv[threadIdx.x] ||
                    (v2 == shv[threadIdx.x] && i2 < shi[threadIdx.x])) {
                    shv[threadIdx.x] = v2;
                    shi[threadIdx.x] = i2;
                }
            }
            __syncthreads();
        }
        if (threadIdx.x == 0) sel[k] = shi[0];
        __syncthreads();
    }

    const float* fb = feat + ((size_t)b * CH + threadIdx.x) * (size_t)NPIX;
    float s = 0.0f;
    for (int j = 0; j < TOPK; ++j) s += fb[sel[j]];
    o[threadIdx.x] = s / (float)TOPK;
}

extern "C" void kernel_launch(void* const* d_in, const int* in_sizes, int n_in,
                              void* d_out, int out_size, void* d_ws, size_t ws_size,
                              hipStream_t stream) {
    const float* feat = (const float*)d_in[0];  // (16,256,128,128) fp32
    const float* outp = (const float*)d_in[1];  // (16,2,128,128)  fp32
    const float* tau  = (const float*)d_in[2];  // scalar fp32
    float* dout = (float*)d_out;                // 2 * 16*256 fp32

    uint64_t* mfg = (uint64_t*)d_ws;                         // 32 KB
    uint64_t* mbg = (uint64_t*)((char*)d_ws + (size_t)BS * WPB * 8);

    mask_kernel<<<BS * (NPIX / 256), 256, 0, stream>>>(outp, tau, mfg, mbg);
    sum_kernel<<<BS * CH, 256, 0, stream>>>(feat, mfg, mbg, dout);
    finalize_kernel<<<2 * BS, 256, 0, stream>>>(feat, outp, mfg, mbg, dout);
}